// Round 12
// baseline (56.076 us; speedup 1.0000x reference)
//
#include <hip/hip_runtime.h>

#define D_FEAT 32
#define NB_SHIFT 7                 // 128 nodes per bin
#define NODES_PER_BIN 128
#define MAX_BINS 800               // 782 needed for 100K nodes
#define EBLOCKS 256                // edge-pass blocks
#define ETHREADS 1024              // 16 waves per edge-pass block
#define CAP 2292                   // fixed bin-slot capacity; mean 2048, sd 45 -> +5.4 sigma, %4==0
#define FT 512                     // fused sort+gather threads
#define EITER 2                    // ceil(1563 int4 / 1024 threads)
#define GITER 2                    // ceil(573 int4 / 512 threads)

// Kernel 1 (single-pass hist+reserve+fill): LDS-histogram the chunk (atomic
// return = within-(block,bin) rank, kept in registers with the edge data),
// reserve each bin's sub-range with one global atomicAdd, scatter directly.
// Overflow guard: reservation exceeding CAP -> obase=-1, writes dropped ->
// validation fails loudly, no OOB writes.
__global__ void __launch_bounds__(ETHREADS)
fusedfill_kernel(const int* __restrict__ src, const int* __restrict__ dst,
                 int* __restrict__ cur, int* __restrict__ bucket,
                 int n_edges, int nbins, int chunk) {
    __shared__ int h[MAX_BINS];
    __shared__ int obase[MAX_BINS];
    for (int i = threadIdx.x; i < nbins; i += ETHREADS) h[i] = 0;
    __syncthreads();
    int e0 = blockIdx.x * chunk;               // chunk % 4 == 0 -> 16B aligned
    int e1 = min(e0 + chunk, n_edges);
    int nfull = (e1 - e0) >> 2;
    const int4* d4 = (const int4*)(dst + e0);
    const int4* s4 = (const int4*)(src + e0);
    int4 dv[EITER], sv[EITER], rv[EITER];
    #pragma unroll
    for (int it = 0; it < EITER; ++it) {
        int i = threadIdx.x + it * ETHREADS;
        if (i < nfull) {
            int4 d = d4[i];
            dv[it] = d;
            sv[it] = s4[i];
            rv[it].x = atomicAdd(&h[d.x >> NB_SHIFT], 1);
            rv[it].y = atomicAdd(&h[d.y >> NB_SHIFT], 1);
            rv[it].z = atomicAdd(&h[d.z >> NB_SHIFT], 1);
            rv[it].w = atomicAdd(&h[d.w >> NB_SHIFT], 1);
        }
    }
    int erem = e0 + (nfull << 2) + threadIdx.x;
    int drem = 0, srem = 0, rrem = -1;
    if (erem < e1) {
        drem = dst[erem];
        srem = src[erem];
        rrem = atomicAdd(&h[drem >> NB_SHIFT], 1);
    }
    __syncthreads();
    for (int i = threadIdx.x; i < nbins; i += ETHREADS) {
        int c = h[i];
        if (c > 0) {
            int s = atomicAdd(&cur[i], c);
            obase[i] = (s + c <= CAP) ? (i * CAP + s) : -1;
        } else {
            obase[i] = -1;
        }
    }
    __syncthreads();
    #pragma unroll
    for (int it = 0; it < EITER; ++it) {
        int i = threadIdx.x + it * ETHREADS;
        if (i < nfull) {
            int4 d = dv[it], s = sv[it], r = rv[it];
            int b, ob;
            b = d.x >> NB_SHIFT; ob = obase[b];
            if (ob >= 0) bucket[ob + r.x] = ((d.x & (NODES_PER_BIN - 1)) << 17) | s.x;
            b = d.y >> NB_SHIFT; ob = obase[b];
            if (ob >= 0) bucket[ob + r.y] = ((d.y & (NODES_PER_BIN - 1)) << 17) | s.y;
            b = d.z >> NB_SHIFT; ob = obase[b];
            if (ob >= 0) bucket[ob + r.z] = ((d.z & (NODES_PER_BIN - 1)) << 17) | s.z;
            b = d.w >> NB_SHIFT; ob = obase[b];
            if (ob >= 0) bucket[ob + r.w] = ((d.w & (NODES_PER_BIN - 1)) << 17) | s.w;
        }
    }
    if (rrem >= 0) {
        int b = drem >> NB_SHIFT;
        int ob = obase[b];
        if (ob >= 0) bucket[ob + rrem] = ((drem & (NODES_PER_BIN - 1)) << 17) | srem;
    }
}

// Kernel 2 (fused sort+gather): one block per bin. Register-stage the slice,
// count-pass atomic returns within-node rank, scan, single sorted LDS write.
// Gather: 64 groups of 8 lanes; lane k owns float4 chunk k of the 128B row;
// unroll 4 with dual accumulators. Single float4 store per node.
__global__ void __launch_bounds__(FT)
sortgather_kernel(const float* __restrict__ hidden,
                  const int* __restrict__ bucket,
                  const int* __restrict__ cur,
                  float* __restrict__ out, int n_nodes) {
    __shared__ int stageB[CAP];
    __shared__ int cnt[NODES_PER_BIN];
    __shared__ int base[NODES_PER_BIN];
    __shared__ int sc[NODES_PER_BIN];
    int bin = blockIdx.x;
    int t = threadIdx.x;
    int m = min(cur[bin], CAP);
    int p0 = bin * CAP;
    if (t < NODES_PER_BIN) cnt[t] = 0;
    __syncthreads();
    int nfull = m >> 2;
    const int4* b4 = (const int4*)(bucket + p0);
    int4 vv[GITER], rk[GITER];
    #pragma unroll
    for (int it = 0; it < GITER; ++it) {
        int i = t + it * FT;
        if (i < nfull) {
            int4 v = b4[i];
            vv[it] = v;
            rk[it].x = atomicAdd(&cnt[v.x >> 17], 1);
            rk[it].y = atomicAdd(&cnt[v.y >> 17], 1);
            rk[it].z = atomicAdd(&cnt[v.z >> 17], 1);
            rk[it].w = atomicAdd(&cnt[v.w >> 17], 1);
        }
    }
    int irem = (nfull << 2) + t;
    int vrem = 0, rkrem = -1;
    if (irem < m) {
        vrem = bucket[p0 + irem];
        rkrem = atomicAdd(&cnt[vrem >> 17], 1);
    }
    __syncthreads();
    if (t < NODES_PER_BIN) sc[t] = cnt[t];
    __syncthreads();
    for (int off = 1; off < NODES_PER_BIN; off <<= 1) {
        int v = (t >= off && t < NODES_PER_BIN) ? sc[t - off] : 0;
        __syncthreads();
        if (t < NODES_PER_BIN) sc[t] += v;
        __syncthreads();
    }
    if (t < NODES_PER_BIN) base[t] = sc[t] - cnt[t];
    __syncthreads();
    #pragma unroll
    for (int it = 0; it < GITER; ++it) {
        int i = t + it * FT;
        if (i < nfull) {
            int4 v = vv[it], r = rk[it];
            stageB[base[v.x >> 17] + r.x] = v.x & 0x1FFFF;
            stageB[base[v.y >> 17] + r.y] = v.y & 0x1FFFF;
            stageB[base[v.z >> 17] + r.z] = v.z & 0x1FFFF;
            stageB[base[v.w >> 17] + r.w] = v.w & 0x1FFFF;
        }
    }
    if (rkrem >= 0)
        stageB[base[vrem >> 17] + rkrem] = vrem & 0x1FFFF;
    __syncthreads();
    // gather: 8-lane groups, float4 per lane
    int gg = t >> 3;              // 64 node-groups
    int l8 = t & 7;               // float4 chunk index
    const float4* h4 = (const float4*)hidden;
    float4* o4 = (float4*)out;
    int nbase = bin << NB_SHIFT;
    for (int ln = gg; ln < NODES_PER_BIN; ln += FT / 8) {
        int node = nbase + ln;
        if (node >= n_nodes) break;    // node increases with ln
        int c = cnt[ln];
        float4 a0 = make_float4(0.f, 0.f, 0.f, 0.f);
        if (c == 0) {
            o4[(size_t)node * 8 + l8] = h4[(size_t)node * 8 + l8];
            continue;
        }
        float4 a1 = make_float4(0.f, 0.f, 0.f, 0.f);
        int p = base[ln];
        int e = p + c;
        for (; p + 4 <= e; p += 4) {
            int v0 = stageB[p + 0], v1 = stageB[p + 1];
            int v2 = stageB[p + 2], v3 = stageB[p + 3];
            float4 x0 = h4[(size_t)v0 * 8 + l8];
            float4 x1 = h4[(size_t)v1 * 8 + l8];
            float4 x2 = h4[(size_t)v2 * 8 + l8];
            float4 x3 = h4[(size_t)v3 * 8 + l8];
            a0.x += x0.x; a0.y += x0.y; a0.z += x0.z; a0.w += x0.w;
            a1.x += x1.x; a1.y += x1.y; a1.z += x1.z; a1.w += x1.w;
            a0.x += x2.x; a0.y += x2.y; a0.z += x2.z; a0.w += x2.w;
            a1.x += x3.x; a1.y += x3.y; a1.z += x3.z; a1.w += x3.w;
        }
        if (p + 2 <= e) {
            int v0 = stageB[p + 0], v1 = stageB[p + 1];
            float4 x0 = h4[(size_t)v0 * 8 + l8];
            float4 x1 = h4[(size_t)v1 * 8 + l8];
            a0.x += x0.x; a0.y += x0.y; a0.z += x0.z; a0.w += x0.w;
            a1.x += x1.x; a1.y += x1.y; a1.z += x1.z; a1.w += x1.w;
            p += 2;
        }
        if (p < e) {
            float4 x0 = h4[(size_t)stageB[p] * 8 + l8];
            a0.x += x0.x; a0.y += x0.y; a0.z += x0.z; a0.w += x0.w;
        }
        a0.x += a1.x; a0.y += a1.y; a0.z += a1.z; a0.w += a1.w;
        o4[(size_t)node * 8 + l8] = a0;
    }
}

extern "C" void kernel_launch(void* const* d_in, const int* in_sizes, int n_in,
                              void* d_out, int out_size, void* d_ws, size_t ws_size,
                              hipStream_t stream) {
    const float* hidden = (const float*)d_in[0];
    const int* src = (const int*)d_in[1];
    const int* dst = (const int*)d_in[2];
    float* out = (float*)d_out;
    int n_nodes = in_sizes[0] / D_FEAT;
    int n_edges = in_sizes[1];
    int nbins = (n_nodes + NODES_PER_BIN - 1) >> NB_SHIFT;   // 782
    int chunk = (((n_edges + EBLOCKS - 1) / EBLOCKS) + 3) & ~3;  // 6252, %4==0

    // Workspace (bytes): [cur 782*4 = 3,128][pad to 3,200][bucket 782*2292*4 = 7,169,376]
    // Total = 7,172,576 B — proven-safe (rounds 10/11).
    int* cur = (int*)d_ws;
    int* bucket = (int*)((char*)d_ws + 3200);

    hipMemsetAsync(cur, 0, 3200, stream);
    fusedfill_kernel<<<EBLOCKS, ETHREADS, 0, stream>>>(src, dst, cur, bucket,
                                                       n_edges, nbins, chunk);
    sortgather_kernel<<<nbins, FT, 0, stream>>>(hidden, bucket, cur, out, n_nodes);
}

// Round 13
// 54.650 us; speedup vs baseline: 1.0261x; 1.0261x over previous
//
#include <hip/hip_runtime.h>

#define D_FEAT 32
#define NB_SHIFT 7                 // 128 nodes per bin
#define NODES_PER_BIN 128
#define MAX_BINS 800               // 782 needed for 100K nodes
#define EBLOCKS 256                // edge-pass blocks
#define ETHREADS 1024              // 16 waves per edge-pass block
#define CAP 2292                   // fixed bin-slot capacity; mean 2048, sd 45 -> +5.4 sigma, %4==0
#define FT 512                     // fused sort+gather threads
#define EITER 2                    // ceil(1563 int4 / 1024 threads)
#define GITER 2                    // ceil(573 int4 / 512 threads)
#define NTILES 8                   // src tiles: 16K nodes = 2MB of hidden each
#define TSHIFT 14
#define NKEYS (NODES_PER_BIN * NTILES)   // 1024 sort keys = (dstLocal, srcTile)

// key from packed (dl<<17 | src): dl bits 17..23, src bits 0..16, tile = src>>14
#define KEY(v) ((((v) >> 17) << 3) | (((v) >> TSHIFT) & (NTILES - 1)))

// Kernel 1 (single-pass hist+reserve+fill): LDS-histogram the chunk (atomic
// return = within-(block,bin) rank, kept in registers with the edge data),
// reserve each bin's sub-range with one global atomicAdd, scatter directly.
// Overflow guard: reservation exceeding CAP -> obase=-1, writes dropped ->
// validation fails loudly, no OOB writes.
__global__ void __launch_bounds__(ETHREADS)
fusedfill_kernel(const int* __restrict__ src, const int* __restrict__ dst,
                 int* __restrict__ cur, int* __restrict__ bucket,
                 int n_edges, int nbins, int chunk) {
    __shared__ int h[MAX_BINS];
    __shared__ int obase[MAX_BINS];
    for (int i = threadIdx.x; i < nbins; i += ETHREADS) h[i] = 0;
    __syncthreads();
    int e0 = blockIdx.x * chunk;               // chunk % 4 == 0 -> 16B aligned
    int e1 = min(e0 + chunk, n_edges);
    int nfull = (e1 - e0) >> 2;
    const int4* d4 = (const int4*)(dst + e0);
    const int4* s4 = (const int4*)(src + e0);
    int4 dv[EITER], sv[EITER], rv[EITER];
    #pragma unroll
    for (int it = 0; it < EITER; ++it) {
        int i = threadIdx.x + it * ETHREADS;
        if (i < nfull) {
            int4 d = d4[i];
            dv[it] = d;
            sv[it] = s4[i];
            rv[it].x = atomicAdd(&h[d.x >> NB_SHIFT], 1);
            rv[it].y = atomicAdd(&h[d.y >> NB_SHIFT], 1);
            rv[it].z = atomicAdd(&h[d.z >> NB_SHIFT], 1);
            rv[it].w = atomicAdd(&h[d.w >> NB_SHIFT], 1);
        }
    }
    int erem = e0 + (nfull << 2) + threadIdx.x;
    int drem = 0, srem = 0, rrem = -1;
    if (erem < e1) {
        drem = dst[erem];
        srem = src[erem];
        rrem = atomicAdd(&h[drem >> NB_SHIFT], 1);
    }
    __syncthreads();
    for (int i = threadIdx.x; i < nbins; i += ETHREADS) {
        int c = h[i];
        if (c > 0) {
            int s = atomicAdd(&cur[i], c);
            obase[i] = (s + c <= CAP) ? (i * CAP + s) : -1;
        } else {
            obase[i] = -1;
        }
    }
    __syncthreads();
    #pragma unroll
    for (int it = 0; it < EITER; ++it) {
        int i = threadIdx.x + it * ETHREADS;
        if (i < nfull) {
            int4 d = dv[it], s = sv[it], r = rv[it];
            int b, ob;
            b = d.x >> NB_SHIFT; ob = obase[b];
            if (ob >= 0) bucket[ob + r.x] = ((d.x & (NODES_PER_BIN - 1)) << 17) | s.x;
            b = d.y >> NB_SHIFT; ob = obase[b];
            if (ob >= 0) bucket[ob + r.y] = ((d.y & (NODES_PER_BIN - 1)) << 17) | s.y;
            b = d.z >> NB_SHIFT; ob = obase[b];
            if (ob >= 0) bucket[ob + r.z] = ((d.z & (NODES_PER_BIN - 1)) << 17) | s.z;
            b = d.w >> NB_SHIFT; ob = obase[b];
            if (ob >= 0) bucket[ob + r.w] = ((d.w & (NODES_PER_BIN - 1)) << 17) | s.w;
        }
    }
    if (rrem >= 0) {
        int b = drem >> NB_SHIFT;
        int ob = obase[b];
        if (ob >= 0) bucket[ob + rrem] = ((drem & (NODES_PER_BIN - 1)) << 17) | srem;
    }
}

// Kernel 2 (fused sort+gather, src-tiled): one block per bin. Counting-sort the
// bin slice by key=(dstLocal, srcTile) into LDS; gather runs as NTILES phases
// separated by block barriers so the whole machine's random row reads stay
// within one 2MB src window (L2-resident on every XCD). Each 8-lane group owns
// 2 nodes; accumulators live in registers across phases; lane k owns float4
// chunk k of the 128B row.
__global__ void __launch_bounds__(FT)
sortgather_kernel(const float* __restrict__ hidden,
                  const int* __restrict__ bucket,
                  const int* __restrict__ cur,
                  float* __restrict__ out, int n_nodes) {
    __shared__ int stageB[CAP];
    __shared__ int cnt[NKEYS];
    __shared__ int base[NKEYS];
    __shared__ int wsum[8];
    int bin = blockIdx.x;
    int t = threadIdx.x;
    int m = min(cur[bin], CAP);
    int p0 = bin * CAP;
    for (int i = t; i < NKEYS; i += FT) cnt[i] = 0;
    __syncthreads();
    // count pass: atomic return = rank within (node,tile)
    int nfull = m >> 2;
    const int4* b4 = (const int4*)(bucket + p0);
    int4 vv[GITER], rk[GITER];
    #pragma unroll
    for (int it = 0; it < GITER; ++it) {
        int i = t + it * FT;
        if (i < nfull) {
            int4 v = b4[i];
            vv[it] = v;
            rk[it].x = atomicAdd(&cnt[KEY(v.x)], 1);
            rk[it].y = atomicAdd(&cnt[KEY(v.y)], 1);
            rk[it].z = atomicAdd(&cnt[KEY(v.z)], 1);
            rk[it].w = atomicAdd(&cnt[KEY(v.w)], 1);
        }
    }
    int irem = (nfull << 2) + t;
    int vrem = 0, rkrem = -1;
    if (irem < m) {
        vrem = bucket[p0 + irem];
        rkrem = atomicAdd(&cnt[KEY(vrem)], 1);
    }
    __syncthreads();
    // exclusive scan over 1024 keys: 512 threads x 2 counters, two-level shfl
    int c0 = cnt[2 * t], c1 = cnt[2 * t + 1];
    int s = c0 + c1;
    int lane = t & 63, w = t >> 6;
    int pre = s;
    for (int off = 1; off < 64; off <<= 1) {
        int x = __shfl_up(pre, off, 64);
        if (lane >= off) pre += x;
    }
    if (lane == 63) wsum[w] = pre;
    __syncthreads();
    if (t < 64) {
        int x = (lane < 8) ? wsum[lane] : 0;
        int p2 = x;
        for (int off = 1; off < 8; off <<= 1) {
            int y = __shfl_up(p2, off, 64);
            if (lane >= off) p2 += y;
        }
        if (lane < 8) wsum[lane] = p2 - x;   // exclusive wave offsets
    }
    __syncthreads();
    int excl = pre - s + wsum[w];
    base[2 * t] = excl;
    base[2 * t + 1] = excl + c0;
    __syncthreads();
    // sorted write
    #pragma unroll
    for (int it = 0; it < GITER; ++it) {
        int i = t + it * FT;
        if (i < nfull) {
            int4 v = vv[it], r = rk[it];
            stageB[base[KEY(v.x)] + r.x] = v.x & 0x1FFFF;
            stageB[base[KEY(v.y)] + r.y] = v.y & 0x1FFFF;
            stageB[base[KEY(v.z)] + r.z] = v.z & 0x1FFFF;
            stageB[base[KEY(v.w)] + r.w] = v.w & 0x1FFFF;
        }
    }
    if (rkrem >= 0)
        stageB[base[KEY(vrem)] + rkrem] = vrem & 0x1FFFF;
    __syncthreads();
    // gather: 64 groups of 8 lanes; group owns nodes gg and gg+64.
    int gg = t >> 3;
    int l8 = t & 7;
    const float4* h4 = (const float4*)hidden;
    float4* o4 = (float4*)out;
    int nbase = bin << NB_SHIFT;
    int ln0 = gg, ln1 = gg + 64;
    float4 a0 = make_float4(0.f, 0.f, 0.f, 0.f);
    float4 a1 = make_float4(0.f, 0.f, 0.f, 0.f);
    int tot0 = 0, tot1 = 0;
    for (int tile = 0; tile < NTILES; ++tile) {
        int k0 = (ln0 << 3) | tile;
        int p = base[k0];
        int e = p + cnt[k0];
        tot0 += cnt[k0];
        for (; p + 2 <= e; p += 2) {
            float4 x0 = h4[(size_t)stageB[p] * 8 + l8];
            float4 x1 = h4[(size_t)stageB[p + 1] * 8 + l8];
            a0.x += x0.x; a0.y += x0.y; a0.z += x0.z; a0.w += x0.w;
            a0.x += x1.x; a0.y += x1.y; a0.z += x1.z; a0.w += x1.w;
        }
        if (p < e) {
            float4 x0 = h4[(size_t)stageB[p] * 8 + l8];
            a0.x += x0.x; a0.y += x0.y; a0.z += x0.z; a0.w += x0.w;
        }
        int k1 = (ln1 << 3) | tile;
        p = base[k1];
        e = p + cnt[k1];
        tot1 += cnt[k1];
        for (; p + 2 <= e; p += 2) {
            float4 x0 = h4[(size_t)stageB[p] * 8 + l8];
            float4 x1 = h4[(size_t)stageB[p + 1] * 8 + l8];
            a1.x += x0.x; a1.y += x0.y; a1.z += x0.z; a1.w += x0.w;
            a1.x += x1.x; a1.y += x1.y; a1.z += x1.z; a1.w += x1.w;
        }
        if (p < e) {
            float4 x0 = h4[(size_t)stageB[p] * 8 + l8];
            a1.x += x0.x; a1.y += x0.y; a1.z += x0.z; a1.w += x0.w;
        }
        __syncthreads();   // phase barrier: keeps the block inside one src tile
    }
    int node0 = nbase + ln0;
    if (node0 < n_nodes) {
        if (tot0 == 0) a0 = h4[(size_t)node0 * 8 + l8];
        o4[(size_t)node0 * 8 + l8] = a0;
    }
    int node1 = nbase + ln1;
    if (node1 < n_nodes) {
        if (tot1 == 0) a1 = h4[(size_t)node1 * 8 + l8];
        o4[(size_t)node1 * 8 + l8] = a1;
    }
}

extern "C" void kernel_launch(void* const* d_in, const int* in_sizes, int n_in,
                              void* d_out, int out_size, void* d_ws, size_t ws_size,
                              hipStream_t stream) {
    const float* hidden = (const float*)d_in[0];
    const int* src = (const int*)d_in[1];
    const int* dst = (const int*)d_in[2];
    float* out = (float*)d_out;
    int n_nodes = in_sizes[0] / D_FEAT;
    int n_edges = in_sizes[1];
    int nbins = (n_nodes + NODES_PER_BIN - 1) >> NB_SHIFT;   // 782
    int chunk = (((n_edges + EBLOCKS - 1) / EBLOCKS) + 3) & ~3;  // 6252, %4==0

    // Workspace (bytes): [cur 782*4 = 3,128][pad to 3,200][bucket 782*2292*4 = 7,169,376]
    // Total = 7,172,576 B — proven-safe (rounds 10-12).
    int* cur = (int*)d_ws;
    int* bucket = (int*)((char*)d_ws + 3200);

    hipMemsetAsync(cur, 0, 3200, stream);
    fusedfill_kernel<<<EBLOCKS, ETHREADS, 0, stream>>>(src, dst, cur, bucket,
                                                       n_edges, nbins, chunk);
    sortgather_kernel<<<nbins, FT, 0, stream>>>(hidden, bucket, cur, out, n_nodes);
}